// Round 11
// baseline (244.825 us; speedup 1.0000x reference)
//
#include <hip/hip_runtime.h>
#include <math.h>

// QTGNN: GRU(10 steps, hidden16) -> QGAT layer1 -> QGAT layer2 -> linear head.
// N=10000 nodes, E=320000 edges (+N self loops). All fp32.
// R1-R8: see git history (GRU shfl matvec; CSR gather; 1 lane/edge segscan).
// R9: circuit -> per-src 4x4 quadratic form (absmax 0.0, exact).
// R10: fused prep into k_gru/k_nodeprep. k_gru became top kernel: 62.9us,
//      VALU 15.6%, occ 25% (grid 625 blocks = 2.4/CU), 1.18M LDS conflicts,
//      WRITE 12.2MB vs 2.5MB logical (scattered T stores).
// R11: (1) 32 lanes/node -> 1250 blocks, GRU k-sum split across 2 half-lanes
//      (serial chain halved), prep on low 16-lane group only (extra waves do
//      the hiding); (2) T staged in LDS, block-copied coalesced; (3) sW padded
//      to stride 17 (kills 8-way b128 conflict). prep_node algebra unchanged.

#define GH 16
#define SEQ 10
#define PI_F 3.14159265358979323846f

__device__ __forceinline__ float sigmoidf_(float x) { return 1.0f / (1.0f + expf(-x)); }

// ---------------- quantum gate helpers (used by k_gmat only) ----------------
template <int STR>
__device__ __forceinline__ void ry_g(float (&sr)[16], float (&si)[16], float c, float s) {
#pragma unroll
    for (int i0 = 0; i0 < 16; ++i0) {
        if (i0 & STR) continue;
        int i1 = i0 | STR;
        float a0r = sr[i0], a0i = si[i0], a1r = sr[i1], a1i = si[i1];
        sr[i0] = c * a0r - s * a1r; si[i0] = c * a0i - s * a1i;
        sr[i1] = s * a0r + c * a1r; si[i1] = s * a0i + c * a1i;
    }
}
template <int STR>
__device__ __forceinline__ void rz_g(float (&sr)[16], float (&si)[16], float c, float s) {
#pragma unroll
    for (int i = 0; i < 16; ++i) {
        float r = sr[i], im = si[i];
        if (i & STR) { sr[i] = r * c - im * s; si[i] = im * c + r * s; }
        else         { sr[i] = r * c + im * s; si[i] = im * c - r * s; }
    }
}
template <int SC, int ST>
__device__ __forceinline__ void cnot_g(float (&sr)[16], float (&si)[16]) {
#pragma unroll
    for (int i = 0; i < 16; ++i) {
        if ((i & SC) && !(i & ST)) {
            int j = i | ST;
            float tr = sr[i], ti = si[i];
            sr[i] = sr[j]; si[i] = si[j]; sr[j] = tr; si[j] = ti;
        }
    }
}

// ---------------- build weight-block matrices G[layer][rep] (16x16 complex) ----------------
__global__ __launch_bounds__(128) void k_gmat(
    const float* __restrict__ q1w, const float* __restrict__ q2w,
    float* __restrict__ Gtab)
{
    int t = threadIdx.x;
    if (t >= 96) return;
    int layer = t / 48, rem = t % 48, rep = rem / 16, col = rem % 16;
    const float* qw = layer ? q2w : q1w;
    float sr[16], si[16];
#pragma unroll
    for (int i = 0; i < 16; ++i) { sr[i] = 0.f; si[i] = 0.f; }
    sr[col] = 1.f;
#pragma unroll
    for (int d = 0; d < 2; ++d) {
        float cy, sy, cz, sz;
        sincosf(0.5f * qw[(rep * 2 + d) * 2 + 0], &sy, &cy);
        sincosf(0.5f * qw[(rep * 2 + d) * 2 + 1], &sz, &cz);
        bool lastd = (rep == 2) && (d == 1);
        ry_g<8>(sr, si, cy, sy); if (!lastd) rz_g<8>(sr, si, cz, sz);
        ry_g<4>(sr, si, cy, sy); if (!lastd) rz_g<4>(sr, si, cz, sz);
        ry_g<2>(sr, si, cy, sy); if (!lastd) rz_g<2>(sr, si, cz, sz);
        ry_g<1>(sr, si, cy, sy); if (!lastd) rz_g<1>(sr, si, cz, sz);
        if (d == 0) { cnot_g<8, 4>(sr, si); cnot_g<2, 1>(sr, si); }
        else        { cnot_g<4, 2>(sr, si); }
    }
    float* g = Gtab + layer * 1536 + rep * 512;
#pragma unroll
    for (int i = 0; i < 16; ++i) {
        g[(i * 16 + col) * 2 + 0] = sr[i];
        g[(i * 16 + col) * 2 + 1] = si[i];
    }
}

// ---------------- R9-validated per-node M^w precompute (device fn) ----------------
// lane in [0,16) (all width-16 shfls); writes 44 floats to LDS block Tb.
__device__ __forceinline__ void prep_node(
    int lane, float c0, float s0, float c1, float s1,
    float c2, float s2, float c3, float s3, float hsd,
    const float (&gr)[3][16 * 17], const float (&gi)[3][16 * 17],
    float* __restrict__ Tb)
{
    float pa = (lane & 8) ? 0.f
             : ((lane & 4) ? s1 : c1) * ((lane & 2) ? s2 : c2) * ((lane & 1) ? s3 : c3);
    float pb;
    { float t = __shfl_xor(pa, 8, 16); pb = (lane & 8) ? t : -t; }

    float ar = 0.f, ai = 0.f, br = 0.f, bi = 0.f;
#pragma unroll
    for (int jj = 0; jj < 16; ++jj) {
        float Gr = gr[0][lane * 17 + jj], Gi = gi[0][lane * 17 + jj];
        float xa = __shfl(pa, jj, 16), xb = __shfl(pb, jj, 16);
        ar += Gr * xa; ai += Gi * xa; br += Gr * xb; bi += Gi * xb;
    }

#define BFLY(vr, vi, STR, cc, ss) { \
    float tr_ = __shfl_xor(vr, STR, 16), ti_ = __shfl_xor(vi, STR, 16); \
    float sg_ = (lane & STR) ? (ss) : -(ss); \
    vr = (cc) * vr + sg_ * tr_; vi = (cc) * vi + sg_ * ti_; }
#define R123(vr, vi) { BFLY(vr, vi, 4, c1, s1) BFLY(vr, vi, 2, c2, s2) BFLY(vr, vi, 1, c3, s3) }
#define KAPP(orr, oii, xr, xi) { \
    float tr_ = __shfl_xor(xr, 8, 16), ti_ = __shfl_xor(xi, 8, 16); \
    orr = (lane & 8) ? tr_ : -tr_; oii = (lane & 8) ? ti_ : -ti_; }

    R123(ar, ai) R123(br, bi)

    float sr4[4], si4[4];
    sr4[0] = ar; si4[0] = ai;
    KAPP(sr4[1], si4[1], ar, ai)
    sr4[2] = br; si4[2] = bi;
    KAPP(sr4[3], si4[3], br, bi)

    float nr4[4] = {0.f, 0.f, 0.f, 0.f}, ni4[4] = {0.f, 0.f, 0.f, 0.f};
#pragma unroll
    for (int jj = 0; jj < 16; ++jj) {
        float Gr = gr[1][lane * 17 + jj], Gi = gi[1][lane * 17 + jj];
#pragma unroll
        for (int v = 0; v < 4; ++v) {
            float xr = __shfl(sr4[v], jj, 16), xi = __shfl(si4[v], jj, 16);
            nr4[v] += Gr * xr - Gi * xi;
            ni4[v] += Gr * xi + Gi * xr;
        }
    }
#pragma unroll
    for (int v = 0; v < 4; ++v) { R123(nr4[v], ni4[v]) }

    float gr4[4], gi4[4];
    float m01r = nr4[1] + nr4[2], m01i = ni4[1] + ni4[2];
    gr4[0] = nr4[0]; gi4[0] = ni4[0];
    { float kr, ki; KAPP(kr, ki, nr4[0], ni4[0]) gr4[1] = m01r + kr; gi4[1] = m01i + ki; }
    { float kr, ki; KAPP(kr, ki, m01r, m01i)     gr4[2] = nr4[3] + kr; gi4[2] = ni4[3] + ki; }
    { float kr, ki; KAPP(kr, ki, nr4[3], ni4[3]) gr4[3] = kr; gi4[3] = ki; }

    float vr4[4] = {0.f, 0.f, 0.f, 0.f}, vi4[4] = {0.f, 0.f, 0.f, 0.f};
#pragma unroll
    for (int jj = 0; jj < 16; ++jj) {
        float Gr = gr[2][lane * 17 + jj], Gi = gi[2][lane * 17 + jj];
#pragma unroll
        for (int v = 0; v < 4; ++v) {
            float xr = __shfl(gr4[v], jj, 16), xi = __shfl(gi4[v], jj, 16);
            vr4[v] += Gr * xr - Gi * xi;
            vi4[v] += Gr * xi + Gi * xr;
        }
    }

    float p[10];
    {
        int idx = 0;
#pragma unroll
        for (int k = 0; k < 4; ++k)
#pragma unroll
            for (int l = 0; l < 4; ++l) {
                if (l < k) continue;
                p[idx++] = vr4[k] * vr4[l] + vi4[k] * vi4[l];
            }
    }
#pragma unroll
    for (int pi = 0; pi < 10; ++pi) {
        float v = p[pi];
#pragma unroll
        for (int m = 8; m >= 1; m >>= 1) {
            float t = __shfl_xor(v, m, 16);
            v = (lane & m) ? (t - v) : (v + t);
        }
        p[pi] = v;
    }

    int w = (lane == 8) ? 0 : (lane == 4) ? 1 : (lane == 2) ? 2 : (lane == 1) ? 3 : -1;
    if (w >= 0) {
#pragma unroll
        for (int pi = 0; pi < 10; ++pi) {
            float mult = (pi == 0 || pi == 4 || pi == 7 || pi == 9) ? 1.f : 2.f;
            Tb[w * 10 + pi] = mult * p[pi];
        }
    }
    if (lane == 0) { Tb[40] = c0; Tb[41] = s0; Tb[42] = hsd; Tb[43] = 0.f; }
#undef BFLY
#undef R123
#undef KAPP
}

// ---------------- GRU (32 lanes/node) + proj1 + FUSED layer-1 prep
//                  + dst-degree histogram + S zeroing ----------------
// Block = 256 threads = 8 nodes x 32 lanes. j = L&15 (hidden unit),
// half = L>>4 (k-range). h replicated across both 16-lane halves.
__global__ __launch_bounds__(256) void k_gru(
    const float* __restrict__ x, const float* __restrict__ W_ih,
    const float* __restrict__ W_hh, const float* __restrict__ b_ih,
    const float* __restrict__ b_hh, const float* __restrict__ p1W,
    const float* __restrict__ p1b, const float* __restrict__ a1W,
    const float* __restrict__ Gl, const int* __restrict__ ei,
    int* __restrict__ deg, float* __restrict__ nres1,
    float* __restrict__ hdd1, float* __restrict__ T,
    float* __restrict__ Sz, int N, int E)
{
    for (int i = blockIdx.x * 256 + threadIdx.x; i < N * 10; i += gridDim.x * 256)
        Sz[i] = 0.f;
    for (int e = blockIdx.x * 256 + threadIdx.x; e < E; e += gridDim.x * 256)
        atomicAdd(&deg[ei[E + e]], 1);

    __shared__ float sW[48 * 17];               // padded stride 17
    __shared__ float sp1W[4 * 19], sp1b[4];
    __shared__ float gr[3][16 * 17], gi[3][16 * 17];
    __shared__ float sT[8 * 48];                // coalesced T staging
    for (int i = threadIdx.x; i < 48 * 16; i += 256)
        sW[(i >> 4) * 17 + (i & 15)] = W_hh[i];
    if (threadIdx.x < 76) sp1W[threadIdx.x] = p1W[threadIdx.x];
    if (threadIdx.x < 4) sp1b[threadIdx.x] = p1b[threadIdx.x];
    for (int idx = threadIdx.x; idx < 3 * 256; idx += 256) {
        int rep = idx >> 8, rc = idx & 255, i = rc >> 4, jj = rc & 15;
        gr[rep][i * 17 + jj] = Gl[rep * 512 + rc * 2 + 0];
        gi[rep][i * 17 + jj] = Gl[rep * 512 + rc * 2 + 1];
    }
    __syncthreads();

    const int L = threadIdx.x & 31;
    const int j = L & 15;
    const int half = L >> 4;
    const int nib = threadIdx.x >> 5;           // node in block (0..7)
    const int n = blockIdx.x * 8 + nib;
    const bool valid = (n < N);

    // 8 weights per gate row for this lane's k-half
    float wr8[8], wz8[8], wn8[8];
#pragma unroll
    for (int kk = 0; kk < 8; ++kk) {
        int k = half * 8 + kk;
        wr8[kk] = sW[j * 17 + k];
        wz8[kk] = sW[(16 + j) * 17 + k];
        wn8[kk] = sW[(32 + j) * 17 + k];
    }
    float wir = W_ih[j], wiz = W_ih[16 + j], win_ = W_ih[32 + j];
    float bir = b_ih[j], biz = b_ih[16 + j], bin_ = b_ih[32 + j];
    float brr = b_hh[j], brz = b_hh[16 + j], brn = b_hh[32 + j];

    float xv[13];
#pragma unroll
    for (int t = 0; t < 13; ++t) xv[t] = valid ? x[n * 13 + t] : 0.f;

    float h = 0.f;                              // h[j], replicated in both halves
#pragma unroll
    for (int t = 0; t < SEQ; ++t) {
        float xt = xv[t];
        float pr = 0.f, pz = 0.f, pn = 0.f;
#pragma unroll
        for (int kk = 0; kk < 8; ++kk) {
            float hk = __shfl(h, half * 8 + kk, 16);
            pr += wr8[kk] * hk; pz += wz8[kk] * hk; pn += wn8[kk] * hk;
        }
        pr += __shfl_xor(pr, 16, 32);
        pz += __shfl_xor(pz, 16, 32);
        pn += __shfl_xor(pn, 16, 32);
        float r  = sigmoidf_(xt * wir + bir + brr + pr);
        float z  = sigmoidf_(xt * wiz + biz + brz + pz);
        float nv = tanhf(xt * win_ + bin_ + r * (brn + pn));
        h = (1.f - z) * nv + z * h;
    }

    // proj1 via 16-lane butterfly (h replicated -> both halves identical)
    float b0 = h * sp1W[0 * 19 + j];
    float b1 = h * sp1W[1 * 19 + j];
    float b2 = h * sp1W[2 * 19 + j];
    float b3 = h * sp1W[3 * 19 + j];
#pragma unroll
    for (int m = 1; m < 16; m <<= 1) {
        b0 += __shfl_xor(b0, m, 16);
        b1 += __shfl_xor(b1, m, 16);
        b2 += __shfl_xor(b2, m, 16);
        b3 += __shfl_xor(b3, m, 16);
    }

    float hv = 0.f, cv = 1.f, sv = 0.f, ds = 0.f, dd = 0.f;
    if (j < 4) {
        float s = (j == 0) ? b0 : (j == 1) ? b1 : (j == 2) ? b2 : b3;
        s += sp1b[j] + xv[10] * sp1W[j * 19 + 16] + xv[11] * sp1W[j * 19 + 17]
           + xv[12] * sp1W[j * 19 + 18];
        hv = (s > 0.f) ? s : expm1f(s);
        sincosf(0.5f * PI_F * tanhf(hv), &sv, &cv);
        ds = hv * a1W[j];
        dd = hv * a1W[4 + j];
    }
    ds += __shfl_xor(ds, 1, 16); ds += __shfl_xor(ds, 2, 16);
    dd += __shfl_xor(dd, 1, 16); dd += __shfl_xor(dd, 2, 16);

    float c0 = __shfl(cv, 0, 16), s0 = __shfl(sv, 0, 16);
    float c1 = __shfl(cv, 1, 16), s1 = __shfl(sv, 1, 16);
    float c2 = __shfl(cv, 2, 16), s2 = __shfl(sv, 2, 16);
    float c3 = __shfl(cv, 3, 16), s3 = __shfl(sv, 3, 16);
    float hsd = __shfl(ds, 0, 16);

    if (valid) {
        if (L < 4) nres1[n * 4 + L] = hv;
        if (L == 0) hdd1[n] = dd;
    }
    if (L < 16)   // prep on low half only; extra resident waves hide latency
        prep_node(j, c0, s0, c1, s1, c2, s2, c3, s3, hsd, gr, gi, sT + nib * 48);
    __syncthreads();
    // coalesced T copy: 8 nodes x 48 floats contiguous
    {
        int n0 = blockIdx.x * 8;
        int cnt = (min(n0 + 8, N) - n0) * 48;
        for (int i = threadIdx.x; i < cnt; i += 256)
            T[(size_t)n0 * 48 + i] = sT[i];
    }
}

// ---------------- offsets (deg+1 incl. self-loop) ----------------
__global__ __launch_bounds__(1024) void k_scan(
    const int* __restrict__ deg, int* __restrict__ off,
    int* __restrict__ cur, int N)
{
    __shared__ int part[1024];
    const int t = threadIdx.x;
    const int chunk = (N + 1023) / 1024;
    const int lo = t * chunk;
    const int hi = min(lo + chunk, N);
    int s = 0;
    for (int i = lo; i < hi; ++i) s += deg[i] + 1;
    part[t] = s;
    __syncthreads();
    for (int d = 1; d < 1024; d <<= 1) {
        int y = (t >= d) ? part[t - d] : 0;
        __syncthreads();
        part[t] += y;
        __syncthreads();
    }
    int run = part[t] - s;
    for (int i = lo; i < hi; ++i) { off[i] = run; cur[i] = run; run += deg[i] + 1; }
}

// ---------------- CSR fill: {src|dst<<16, |ea|, cos, sin} (incl. self-loops) ----------------
__global__ __launch_bounds__(256) void k_fill(
    const int* __restrict__ ei, const float* __restrict__ ea,
    int* __restrict__ cur, float4* __restrict__ rec, int E, int N)
{
    int idx = blockIdx.x * 256 + threadIdx.x;
    if (idx >= E + N) return;
    int src, d; float ev;
    if (idx < E) { src = ei[idx]; d = ei[E + idx]; ev = ea[idx]; }
    else         { src = idx - E; d = src;         ev = 1.0f;    }
    int slot = atomicAdd(&cur[d], 1);
    float scv, ccv; sincosf(0.5f * PI_F * tanhf(ev), &scv, &ccv);
    float4 r;
    r.x = __int_as_float(src | (d << 16));   // N < 65536
    r.y = fabsf(ev);
    r.z = ccv; r.w = scv;
    rec[slot] = r;
}

// segmented wave reduce over equal-dst runs + atomic by segment-last lane
__device__ __forceinline__ void segreduce(
    int dst, int lane, float a0, float a1, float a2, float a3, float a4,
    float* __restrict__ S)
{
    int prevd = __shfl_up(dst, 1);
    bool head = (lane == 0) || (prevd != dst);
    unsigned long long hm = __ballot(head);
    unsigned long long below = (2ull << lane) - 1ull;
    int H = 63 - __clzll((long long)(hm & below));
    int dist = lane - H;
#pragma unroll
    for (int st = 1; st < 64; st <<= 1) {
        float t0 = __shfl_up(a0, st), t1 = __shfl_up(a1, st),
              t2 = __shfl_up(a2, st), t3 = __shfl_up(a3, st),
              t4 = __shfl_up(a4, st);
        if (dist >= st) { a0 += t0; a1 += t1; a2 += t2; a3 += t3; a4 += t4; }
    }
    int nextd = __shfl_down(dst, 1);
    bool lastl = (lane == 63) || (dst != nextd);
    if (lastl && dst >= 0) {
        float* sbase = S + (size_t)dst * 5;
        atomicAdd(sbase + 0, a0); atomicAdd(sbase + 1, a1);
        atomicAdd(sbase + 2, a2); atomicAdd(sbase + 3, a3);
        atomicAdd(sbase + 4, a4);
    }
}

// ---------------- edge kernel: quadratic form z_w = c^T M^w c ----------------
__global__ __launch_bounds__(256) void k_edge(
    const float4* __restrict__ rec, const float* __restrict__ T,
    const float* __restrict__ hdd, float* __restrict__ S, int EN)
{
    const int slot = blockIdx.x * 256 + threadIdx.x;
    const int lane = threadIdx.x & 63;
    int dst = -1;
    float acc0 = 0.f, acc1 = 0.f, acc2 = 0.f, acc3 = 0.f, acc4 = 0.f;

    if (slot < EN) {
        float4 r = rec[slot];
        int ids = __float_as_int(r.x);
        int src = ids & 0xFFFF;
        dst = ids >> 16;
        float aea = r.y, ccv = r.z, scv = r.w;

        const float* Tb = T + (size_t)src * 48;
        float t[44];
#pragma unroll
        for (int q = 0; q < 11; ++q) {
            float4 v4 = *reinterpret_cast<const float4*>(Tb + q * 4);
            t[q * 4 + 0] = v4.x; t[q * 4 + 1] = v4.y;
            t[q * 4 + 2] = v4.z; t[q * 4 + 3] = v4.w;
        }
        float hdN = hdd[dst];

        float mc = t[40] * ccv - t[41] * scv;
        float ms = t[41] * ccv + t[40] * scv;
        float m2 = mc * mc, s2 = ms * ms;
        float cf0 = mc * m2, cf1 = m2 * ms, cf2 = mc * s2, cf3 = ms * s2;
        float qq[10];
        qq[0] = cf0 * cf0; qq[1] = cf0 * cf1; qq[2] = cf0 * cf2; qq[3] = cf0 * cf3;
        qq[4] = cf1 * cf1; qq[5] = cf1 * cf2; qq[6] = cf1 * cf3;
        qq[7] = cf2 * cf2; qq[8] = cf2 * cf3; qq[9] = cf3 * cf3;

        float z0 = 0.f, z1 = 0.f, z2 = 0.f, z3 = 0.f;
#pragma unroll
        for (int pi = 0; pi < 10; ++pi) {
            z0 += t[pi] * qq[pi];
            z1 += t[10 + pi] * qq[pi];
            z2 += t[20 + pi] * qq[pi];
            z3 += t[30 + pi] * qq[pi];
        }

        float s0a = t[42] + hdN;
        s0a = (s0a > 0.f) ? s0a : 0.2f * s0a;
        float aexp = expf(s0a * aea);
        acc0 = aexp * z0; acc1 = aexp * z1; acc2 = aexp * z2; acc3 = aexp * z3;
        acc4 = aexp;
    }
    segreduce(dst, lane, acc0, acc1, acc2, acc3, acc4, S);
}

// ---------------- layer-1 node update (32 lanes/node) + FUSED layer-2 prep ----------------
__global__ __launch_bounds__(256) void k_nodeprep(
    const float* __restrict__ S, const float* __restrict__ nres,
    const float* __restrict__ g4, const float* __restrict__ be4,
    const float* __restrict__ pW, const float* __restrict__ pb,
    const float* __restrict__ WaN, const float* __restrict__ Gl,
    float* __restrict__ onres, float* __restrict__ ohdd,
    float* __restrict__ T, int N)
{
    __shared__ float gr[3][16 * 17], gi[3][16 * 17];
    __shared__ float sT[8 * 48];
    for (int idx = threadIdx.x; idx < 3 * 256; idx += 256) {
        int rep = idx >> 8, rc = idx & 255, i = rc >> 4, jj = rc & 15;
        gr[rep][i * 17 + jj] = Gl[rep * 512 + rc * 2 + 0];
        gi[rep][i * 17 + jj] = Gl[rep * 512 + rc * 2 + 1];
    }
    __syncthreads();

    const int L = threadIdx.x & 31;
    const int j = L & 15;
    const int nib = threadIdx.x >> 5;
    const int n = blockIdx.x * 8 + nib;
    const bool valid = (n < N);

    float hv[4] = {0.f, 0.f, 0.f, 0.f};
    if (valid) {
        const float* sb = S + (size_t)n * 5;
        float dn = sb[4] + 1e-8f;
        float v0 = sb[0] / dn + nres[n * 4 + 0];
        float v1 = sb[1] / dn + nres[n * 4 + 1];
        float v2 = sb[2] / dn + nres[n * 4 + 2];
        float v3 = sb[3] / dn + nres[n * 4 + 3];
        float mu = 0.25f * (v0 + v1 + v2 + v3);
        float d0 = v0 - mu, d1 = v1 - mu, d2 = v2 - mu, d3 = v3 - mu;
        float var = 0.25f * (d0 * d0 + d1 * d1 + d2 * d2 + d3 * d3);
        float rs = 1.0f / sqrtf(var + 1e-5f);
        float y0 = fmaxf(d0 * rs * g4[0] + be4[0], 0.f);
        float y1 = fmaxf(d1 * rs * g4[1] + be4[1], 0.f);
        float y2 = fmaxf(d2 * rs * g4[2] + be4[2], 0.f);
        float y3 = fmaxf(d3 * rs * g4[3] + be4[3], 0.f);
#pragma unroll
        for (int w = 0; w < 4; ++w) {
            float s = pb[w] + y0 * pW[w * 4 + 0] + y1 * pW[w * 4 + 1]
                    + y2 * pW[w * 4 + 2] + y3 * pW[w * 4 + 3];
            hv[w] = (s > 0.f) ? s : expm1f(s);
        }
    }

    float cv = 1.f, sv = 0.f;
    if (j < 4) sincosf(0.5f * PI_F * tanhf(hv[j]), &sv, &cv);
    float c0 = __shfl(cv, 0, 16), s0 = __shfl(sv, 0, 16);
    float c1 = __shfl(cv, 1, 16), s1 = __shfl(sv, 1, 16);
    float c2 = __shfl(cv, 2, 16), s2 = __shfl(sv, 2, 16);
    float c3 = __shfl(cv, 3, 16), s3 = __shfl(sv, 3, 16);

    float hsd = hv[0] * WaN[0] + hv[1] * WaN[1] + hv[2] * WaN[2] + hv[3] * WaN[3];
    if (valid) {
        if (L < 4) onres[n * 4 + L] = hv[L];
        if (L == 0)
            ohdd[n] = hv[0] * WaN[4] + hv[1] * WaN[5] + hv[2] * WaN[6] + hv[3] * WaN[7];
    }
    if (L < 16)
        prep_node(j, c0, s0, c1, s1, c2, s2, c3, s3, hsd, gr, gi, sT + nib * 48);
    __syncthreads();
    {
        int n0 = blockIdx.x * 8;
        int cnt = (min(n0 + 8, N) - n0) * 48;
        for (int i = threadIdx.x; i < cnt; i += 256)
            T[(size_t)n0 * 48 + i] = sT[i];
    }
}

// ---------------- final node update: norm + residual + LN + head ----------------
__global__ __launch_bounds__(256) void k_node2(
    const float* __restrict__ S, const float* __restrict__ nres,
    const float* __restrict__ g4, const float* __restrict__ be4,
    const float* __restrict__ rW, const float* __restrict__ rb,
    float* __restrict__ out, int N)
{
    int n = blockIdx.x * 256 + threadIdx.x;
    if (n >= N) return;
    const float* sb = S + (size_t)n * 5;
    float dn = sb[4] + 1e-8f;
    float v0 = sb[0] / dn + nres[n * 4 + 0];
    float v1 = sb[1] / dn + nres[n * 4 + 1];
    float v2 = sb[2] / dn + nres[n * 4 + 2];
    float v3 = sb[3] / dn + nres[n * 4 + 3];
    float mu = 0.25f * (v0 + v1 + v2 + v3);
    float d0 = v0 - mu, d1 = v1 - mu, d2 = v2 - mu, d3 = v3 - mu;
    float var = 0.25f * (d0 * d0 + d1 * d1 + d2 * d2 + d3 * d3);
    float rs = 1.0f / sqrtf(var + 1e-5f);
    out[n] = rb[0]
           + (d0 * rs * g4[0] + be4[0]) * rW[0]
           + (d1 * rs * g4[1] + be4[1]) * rW[1]
           + (d2 * rs * g4[2] + be4[2]) * rW[2]
           + (d3 * rs * g4[3] + be4[3]) * rW[3];
}

extern "C" void kernel_launch(void* const* d_in, const int* in_sizes, int n_in,
                              void* d_out, int out_size, void* d_ws, size_t ws_size,
                              hipStream_t stream)
{
    const float* x    = (const float*)d_in[0];
    const int*   ei   = (const int*)d_in[1];
    const float* ea   = (const float*)d_in[2];
    const float* W_ih = (const float*)d_in[3];
    const float* W_hh = (const float*)d_in[4];
    const float* b_ih = (const float*)d_in[5];
    const float* b_hh = (const float*)d_in[6];
    const float* p1W  = (const float*)d_in[7];
    const float* p1b  = (const float*)d_in[8];
    const float* a1W  = (const float*)d_in[9];
    const float* q1w  = (const float*)d_in[10];
    const float* g1   = (const float*)d_in[11];
    const float* be1  = (const float*)d_in[12];
    const float* p2W  = (const float*)d_in[13];
    const float* p2b  = (const float*)d_in[14];
    const float* a2W  = (const float*)d_in[15];
    const float* q2w  = (const float*)d_in[16];
    const float* g2   = (const float*)d_in[17];
    const float* be2  = (const float*)d_in[18];
    const float* rW   = (const float*)d_in[19];
    const float* rb   = (const float*)d_in[20];
    float* out = (float*)d_out;

    int N  = in_sizes[0] / 13;
    int E  = in_sizes[1] / 2;
    int EN = E + N;

    // workspace layout
    float* ws    = (float*)d_ws;
    float* nres1 = ws;                           // N*4
    float* nres2 = nres1 + (size_t)N * 4;        // N*4
    float* hdd1  = nres2 + (size_t)N * 4;        // N
    float* hdd2  = hdd1 + N;                     // N
    float* S1    = hdd2 + N;                     // N*5 (zeroed in k_gru)
    float* S2    = S1 + (size_t)N * 5;           // N*5 (zeroed in k_gru)
    float* Gtab  = S2 + (size_t)N * 5;           // 3072
    float* T     = Gtab + 3072;                  // N*48 (reused across layers)
    int* deg  = (int*)(T + (size_t)N * 48);      // N (memset)
    int* off  = deg + N;                         // N
    int* cur  = off + N;                         // N
    uintptr_t rp = (uintptr_t)(cur + N);
    rp = (rp + 15u) & ~(uintptr_t)15u;           // 16B align
    float4* rec = (float4*)rp;                   // EN float4

    hipMemsetAsync(deg, 0, (size_t)N * sizeof(int), stream);

    const int B = 256;
    k_gmat<<<1, 128, 0, stream>>>(q1w, q2w, Gtab);
    k_gru<<<(N + 7) / 8, B, 0, stream>>>(x, W_ih, W_hh, b_ih, b_hh, p1W, p1b,
                                         a1W, Gtab, ei, deg, nres1, hdd1, T,
                                         S1, N, E);
    k_scan<<<1, 1024, 0, stream>>>(deg, off, cur, N);
    k_fill<<<(EN + B - 1) / B, B, 0, stream>>>(ei, ea, cur, rec, E, N);

    // layer 1
    k_edge<<<(EN + B - 1) / B, B, 0, stream>>>(rec, T, hdd1, S1, EN);
    k_nodeprep<<<(N + 7) / 8, B, 0, stream>>>(
        S1, nres1, g1, be1, p2W, p2b, a2W, Gtab + 1536, nres2, hdd2, T, N);

    // layer 2
    k_edge<<<(EN + B - 1) / B, B, 0, stream>>>(rec, T, hdd2, S2, EN);
    k_node2<<<(N + B - 1) / B, B, 0, stream>>>(S2, nres2, g2, be2, rW, rb, out, N);
}

// Round 14
// 242.541 us; speedup vs baseline: 1.0094x; 1.0094x over previous
//
#include <hip/hip_runtime.h>
#include <math.h>

// QTGNN: GRU(10 steps, hidden16) -> QGAT layer1 -> QGAT layer2 -> linear head.
// N=10000 nodes, E=320000 edges (+N self loops). All fp32.
// R1-R8: see git history (GRU shfl matvec; CSR gather; 1 lane/edge segscan).
// R9: circuit -> per-src 4x4 quadratic form (absmax 0.0, exact).
// R10: fused prep into k_gru/k_nodeprep (232.8us best). k_gru 62.9us at 25%
//      occupancy: GRID-STARVED (2500 waves / 1024 SIMDs = 2.4/SIMD).
// R11: 32-lane/node REGRESSED (86us): prep ran on L<16 -> half of every wave
//      exec-masked -> 2x prep issue. Also WRITE 12.2MB persisted through
//      staged-T => it's the histogram atomics (320K x 32B RMW), not T.
// R12: 1 WAVE PER NODE (64 lanes, all distinct work): GRU 4-way k-split
//      (4 shfl + 12 FMA + 6 xor per step); prep's 4 binomial vectors map to
//      the 4 16-lane groups (G1/G2 = 16 iters x 1 vector; K-grouping via 5
//      fixed-mask width-64 shfls; pair products split 3/3/2/2 across groups).
//      10000 waves (~9.8/SIMD). Algebra identical to R9-validated prep.
// R13/R14: unchanged resubmissions — R12 lost to GPU acquisition timeout,
//      R13 lost to container failure (both infra; no counters either time).

#define GH 16
#define SEQ 10
#define PI_F 3.14159265358979323846f

__device__ __forceinline__ float sigmoidf_(float x) { return 1.0f / (1.0f + expf(-x)); }

// ---------------- quantum gate helpers (used by k_gmat only) ----------------
template <int STR>
__device__ __forceinline__ void ry_g(float (&sr)[16], float (&si)[16], float c, float s) {
#pragma unroll
    for (int i0 = 0; i0 < 16; ++i0) {
        if (i0 & STR) continue;
        int i1 = i0 | STR;
        float a0r = sr[i0], a0i = si[i0], a1r = sr[i1], a1i = si[i1];
        sr[i0] = c * a0r - s * a1r; si[i0] = c * a0i - s * a1i;
        sr[i1] = s * a0r + c * a1r; si[i1] = s * a0i + c * a1i;
    }
}
template <int STR>
__device__ __forceinline__ void rz_g(float (&sr)[16], float (&si)[16], float c, float s) {
#pragma unroll
    for (int i = 0; i < 16; ++i) {
        float r = sr[i], im = si[i];
        if (i & STR) { sr[i] = r * c - im * s; si[i] = im * c + r * s; }
        else         { sr[i] = r * c + im * s; si[i] = im * c - r * s; }
    }
}
template <int SC, int ST>
__device__ __forceinline__ void cnot_g(float (&sr)[16], float (&si)[16]) {
#pragma unroll
    for (int i = 0; i < 16; ++i) {
        if ((i & SC) && !(i & ST)) {
            int j = i | ST;
            float tr = sr[i], ti = si[i];
            sr[i] = sr[j]; si[i] = si[j]; sr[j] = tr; si[j] = ti;
        }
    }
}

// ---------------- build weight-block matrices G[layer][rep] (16x16 complex) ----------------
__global__ __launch_bounds__(128) void k_gmat(
    const float* __restrict__ q1w, const float* __restrict__ q2w,
    float* __restrict__ Gtab)
{
    int t = threadIdx.x;
    if (t >= 96) return;
    int layer = t / 48, rem = t % 48, rep = rem / 16, col = rem % 16;
    const float* qw = layer ? q2w : q1w;
    float sr[16], si[16];
#pragma unroll
    for (int i = 0; i < 16; ++i) { sr[i] = 0.f; si[i] = 0.f; }
    sr[col] = 1.f;
#pragma unroll
    for (int d = 0; d < 2; ++d) {
        float cy, sy, cz, sz;
        sincosf(0.5f * qw[(rep * 2 + d) * 2 + 0], &sy, &cy);
        sincosf(0.5f * qw[(rep * 2 + d) * 2 + 1], &sz, &cz);
        bool lastd = (rep == 2) && (d == 1);
        ry_g<8>(sr, si, cy, sy); if (!lastd) rz_g<8>(sr, si, cz, sz);
        ry_g<4>(sr, si, cy, sy); if (!lastd) rz_g<4>(sr, si, cz, sz);
        ry_g<2>(sr, si, cy, sy); if (!lastd) rz_g<2>(sr, si, cz, sz);
        ry_g<1>(sr, si, cy, sy); if (!lastd) rz_g<1>(sr, si, cz, sz);
        if (d == 0) { cnot_g<8, 4>(sr, si); cnot_g<2, 1>(sr, si); }
        else        { cnot_g<4, 2>(sr, si); }
    }
    float* g = Gtab + layer * 1536 + rep * 512;
#pragma unroll
    for (int i = 0; i < 16; ++i) {
        g[(i * 16 + col) * 2 + 0] = sr[i];
        g[(i * 16 + col) * 2 + 1] = si[i];
    }
}

// ---------------- 64-lane (1 wave/node) M^w precompute ----------------
// L in [0,64): i = L&15 (element), g = L>>4 (binomial-vector group).
// Same algebra as the R9-validated 16-lane prep; lane mapping changed so all
// 64 lanes do distinct work. Writes 44 floats to LDS block Tb.
__device__ __forceinline__ void prep_node64(
    int L, float c0, float s0, float c1, float s1,
    float c2, float s2, float c3, float s3, float hsd,
    const float (&gr)[3][16 * 17], const float (&gi)[3][16 * 17],
    float* __restrict__ Tb)
{
    const int i = L & 15;
    const int g = L >> 4;
    const float sgn = (i & 8) ? 1.f : -1.f;       // K x [i] = sgn * x[i^8]

#define BFLY16(vr, vi, STR, cc, ss) { \
    float tr_ = __shfl_xor(vr, STR, 16), ti_ = __shfl_xor(vi, STR, 16); \
    float sg_ = (i & STR) ? (ss) : -(ss); \
    vr = (cc) * vr + sg_ * tr_; vi = (cc) * vi + sg_ * ti_; }
#define R123(vr, vi) { BFLY16(vr, vi, 4, c1, s1) BFLY16(vr, vi, 2, c2, s2) BFLY16(vr, vi, 1, c3, s3) }

    // rep-0 product state pa (real), pb = K pa
    float pa = (i & 8) ? 0.f
             : ((i & 4) ? s1 : c1) * ((i & 2) ? s2 : c2) * ((i & 1) ? s3 : c3);
    float pb = sgn * __shfl_xor(pa, 8, 16);

    // G0: groups {0,1} build a (half-k each), {2,3} build b; combine via xor16
    float src = (g < 2) ? pa : pb;
    float vr = 0.f, vi = 0.f;
    const int jlo = (g & 1) * 8;
#pragma unroll
    for (int kk = 0; kk < 8; ++kk) {
        int jj = jlo + kk;
        float Gr = gr[0][i * 17 + jj], Gi = gi[0][i * 17 + jj];
        float xx = __shfl(src, jj, 16);
        vr += Gr * xx; vi += Gi * xx;
    }
    vr += __shfl_xor(vr, 16);
    vi += __shfl_xor(vi, 16);

    R123(vr, vi)

    // s_g: odd groups apply K  (s0=a, s1=Ka, s2=b, s3=Kb)
    {
        float kr = sgn * __shfl_xor(vr, 8, 16);
        float ki = sgn * __shfl_xor(vi, 8, 16);
        if (g & 1) { vr = kr; vi = ki; }
    }

    // G1 matvec (1 vector per group)
    float nr = 0.f, ni = 0.f;
#pragma unroll
    for (int jj = 0; jj < 16; ++jj) {
        float Gr = gr[1][i * 17 + jj], Gi = gi[1][i * 17 + jj];
        float xr = __shfl(vr, jj, 16), xi = __shfl(vi, jj, 16);
        nr += Gr * xr - Gi * xi;
        ni += Gr * xi + Gi * xr;
    }
    R123(nr, ni)

    // K-count grouping: g0=n0; g1=(n1+n2)+K n0; g2=n3+K(n1+n2); g3=K n3
    // masks: m8 -> own[i^8], m16 -> (g^1)[i], m24 -> (g^1)[i^8],
    //        m48 -> (g^3)[i], m56 -> (g^3)[i^8]
    float r8  = __shfl_xor(nr, 8),  i8_ = __shfl_xor(ni, 8);
    float r16 = __shfl_xor(nr, 16), i16 = __shfl_xor(ni, 16);
    float r24 = __shfl_xor(nr, 24), i24 = __shfl_xor(ni, 24);
    float r48 = __shfl_xor(nr, 48), i48 = __shfl_xor(ni, 48);
    float r56 = __shfl_xor(nr, 56), i56 = __shfl_xor(ni, 56);
    float br, bi;
    if (g == 0)      { br = nr;                       bi = ni; }
    else if (g == 1) { br = nr + r48 + sgn * r24;     bi = ni + i48 + sgn * i24; }
    else if (g == 2) { br = r16 + sgn * (r56 + r8);   bi = i16 + sgn * (i56 + i8_); }
    else             { br = sgn * r8;                 bi = sgn * i8_; }

    // G2 matvec
    float wr = 0.f, wi = 0.f;
#pragma unroll
    for (int jj = 0; jj < 16; ++jj) {
        float Gr = gr[2][i * 17 + jj], Gi = gi[2][i * 17 + jj];
        float xr = __shfl(br, jj, 16), xi = __shfl(bi, jj, 16);
        wr += Gr * xr - Gi * xi;
        wi += Gr * xi + Gi * xr;
    }

    // cross-group gather: x16=v[g^1], x32=v[g^2], x48=v[g^3] at same element
    float x16r = __shfl_xor(wr, 16), x16i = __shfl_xor(wi, 16);
    float x32r = __shfl_xor(wr, 32), x32i = __shfl_xor(wi, 32);
    float x48r = __shfl_xor(wr, 48), x48i = __shfl_xor(wi, 48);

    // products per group (3/3/2/2), named to keep static indexing:
    // g0: p00,p01,p02 (pi 0,1,2) = own*own, own*x16(v1), own*x32(v2)
    // g1: p03,p11,p12 (pi 3,4,5) = x16(v0)*x32(v3), own*own, own*x48(v2)
    // g2: p13,p22     (pi 6,7)   = x48(v1)*x16(v3), own*own
    // g3: p23,p33     (pi 8,9)   = x16(v2)*own,     own*own
    float pA, pB, pC = 0.f;
    int piA, piB, piC = -1;
    bool hasC = false;
    if (g == 0) {
        pA = wr * wr + wi * wi;          piA = 0;
        pB = wr * x16r + wi * x16i;      piB = 1;
        pC = wr * x32r + wi * x32i;      piC = 2; hasC = true;
    } else if (g == 1) {
        pA = x16r * x32r + x16i * x32i;  piA = 3;
        pB = wr * wr + wi * wi;          piB = 4;
        pC = wr * x48r + wi * x48i;      piC = 5; hasC = true;
    } else if (g == 2) {
        pA = x48r * x16r + x48i * x16i;  piA = 6;
        pB = wr * wr + wi * wi;          piB = 7;
    } else {
        pA = x16r * wr + x16i * wi;      piA = 8;
        pB = wr * wr + wi * wi;          piB = 9;
    }

    // WHT width 16 on each product (R9 sign convention)
#pragma unroll
    for (int m = 8; m >= 1; m >>= 1) {
        float tA = __shfl_xor(pA, m, 16);
        float tB = __shfl_xor(pB, m, 16);
        float tC = __shfl_xor(pC, m, 16);
        bool hi = (i & m) != 0;
        pA = hi ? (tA - pA) : (pA + tA);
        pB = hi ? (tB - pB) : (pB + tB);
        pC = hi ? (tC - pC) : (pC + tC);
    }

    // lanes i in {8,4,2,1} hold w = 0..3; diag products (0,4,7,9) x1 else x2
    int w = (i == 8) ? 0 : (i == 4) ? 1 : (i == 2) ? 2 : (i == 1) ? 3 : -1;
    if (w >= 0) {
        float mA = (piA == 0 || piA == 4 || piA == 7 || piA == 9) ? 1.f : 2.f;
        float mB = (piB == 0 || piB == 4 || piB == 7 || piB == 9) ? 1.f : 2.f;
        Tb[w * 10 + piA] = mA * pA;
        Tb[w * 10 + piB] = mB * pB;
        if (hasC) Tb[w * 10 + piC] = 2.f * pC;   // pi 2 and 5 are off-diag
    }
    if (L == 0) { Tb[40] = c0; Tb[41] = s0; Tb[42] = hsd; Tb[43] = 0.f; }
#undef BFLY16
#undef R123
}

// ---------------- GRU (1 wave/node) + proj1 + FUSED layer-1 prep
//                  + dst-degree histogram + S zeroing ----------------
// Block = 256 threads = 4 nodes x 64 lanes. j = L&15 (unit), q = L>>4 (k-quarter).
__global__ __launch_bounds__(256) void k_gru(
    const float* __restrict__ x, const float* __restrict__ W_ih,
    const float* __restrict__ W_hh, const float* __restrict__ b_ih,
    const float* __restrict__ b_hh, const float* __restrict__ p1W,
    const float* __restrict__ p1b, const float* __restrict__ a1W,
    const float* __restrict__ Gl, const int* __restrict__ ei,
    int* __restrict__ deg, float* __restrict__ nres1,
    float* __restrict__ hdd1, float* __restrict__ T,
    float* __restrict__ Sz, int N, int E)
{
    for (int i = blockIdx.x * 256 + threadIdx.x; i < N * 10; i += gridDim.x * 256)
        Sz[i] = 0.f;
    for (int e = blockIdx.x * 256 + threadIdx.x; e < E; e += gridDim.x * 256)
        atomicAdd(&deg[ei[E + e]], 1);

    __shared__ float sW[48 * 17];               // padded stride 17
    __shared__ float sp1W[4 * 19], sp1b[4];
    __shared__ float gr[3][16 * 17], gi[3][16 * 17];
    __shared__ float sT[4 * 48];
    for (int i = threadIdx.x; i < 48 * 16; i += 256)
        sW[(i >> 4) * 17 + (i & 15)] = W_hh[i];
    if (threadIdx.x < 76) sp1W[threadIdx.x] = p1W[threadIdx.x];
    if (threadIdx.x < 4) sp1b[threadIdx.x] = p1b[threadIdx.x];
    for (int idx = threadIdx.x; idx < 3 * 256; idx += 256) {
        int rep = idx >> 8, rc = idx & 255, i = rc >> 4, jj = rc & 15;
        gr[rep][i * 17 + jj] = Gl[rep * 512 + rc * 2 + 0];
        gi[rep][i * 17 + jj] = Gl[rep * 512 + rc * 2 + 1];
    }
    __syncthreads();

    const int L = threadIdx.x & 63;
    const int j = L & 15;
    const int q = L >> 4;
    const int nw = threadIdx.x >> 6;            // node (wave) in block, 0..3
    const int n = blockIdx.x * 4 + nw;
    const bool valid = (n < N);

    if (valid) {
        // 4 weights per gate row for this lane's k-quarter
        float wr4[4], wz4[4], wn4[4];
#pragma unroll
        for (int kk = 0; kk < 4; ++kk) {
            int k = q * 4 + kk;
            wr4[kk] = sW[j * 17 + k];
            wz4[kk] = sW[(16 + j) * 17 + k];
            wn4[kk] = sW[(32 + j) * 17 + k];
        }
        float wir = W_ih[j], wiz = W_ih[16 + j], win_ = W_ih[32 + j];
        float bir = b_ih[j], biz = b_ih[16 + j], bin_ = b_ih[32 + j];
        float brr = b_hh[j], brz = b_hh[16 + j], brn = b_hh[32 + j];

        float xv[13];
#pragma unroll
        for (int t = 0; t < 13; ++t) xv[t] = x[n * 13 + t];

        float h = 0.f;                          // h[j], replicated across quarters
#pragma unroll
        for (int t = 0; t < SEQ; ++t) {
            float xt = xv[t];
            float pr = 0.f, pz = 0.f, pn = 0.f;
#pragma unroll
            for (int kk = 0; kk < 4; ++kk) {
                float hk = __shfl(h, q * 4 + kk, 16);
                pr += wr4[kk] * hk; pz += wz4[kk] * hk; pn += wn4[kk] * hk;
            }
            pr += __shfl_xor(pr, 16); pr += __shfl_xor(pr, 32);
            pz += __shfl_xor(pz, 16); pz += __shfl_xor(pz, 32);
            pn += __shfl_xor(pn, 16); pn += __shfl_xor(pn, 32);
            float r  = sigmoidf_(xt * wir + bir + brr + pr);
            float z  = sigmoidf_(xt * wiz + biz + brz + pz);
            float nv = tanhf(xt * win_ + bin_ + r * (brn + pn));
            h = (1.f - z) * nv + z * h;
        }

        // proj1 via 16-lane butterfly (replicated across quarters)
        float b0 = h * sp1W[0 * 19 + j];
        float b1 = h * sp1W[1 * 19 + j];
        float b2 = h * sp1W[2 * 19 + j];
        float b3 = h * sp1W[3 * 19 + j];
#pragma unroll
        for (int m = 1; m < 16; m <<= 1) {
            b0 += __shfl_xor(b0, m, 16);
            b1 += __shfl_xor(b1, m, 16);
            b2 += __shfl_xor(b2, m, 16);
            b3 += __shfl_xor(b3, m, 16);
        }

        float hv = 0.f, cv = 1.f, sv = 0.f, ds = 0.f, dd = 0.f;
        if (j < 4) {
            float s = (j == 0) ? b0 : (j == 1) ? b1 : (j == 2) ? b2 : b3;
            s += sp1b[j] + xv[10] * sp1W[j * 19 + 16] + xv[11] * sp1W[j * 19 + 17]
               + xv[12] * sp1W[j * 19 + 18];
            hv = (s > 0.f) ? s : expm1f(s);
            sincosf(0.5f * PI_F * tanhf(hv), &sv, &cv);
            ds = hv * a1W[j];
            dd = hv * a1W[4 + j];
        }
        ds += __shfl_xor(ds, 1, 16); ds += __shfl_xor(ds, 2, 16);
        dd += __shfl_xor(dd, 1, 16); dd += __shfl_xor(dd, 2, 16);

        float c0 = __shfl(cv, 0, 16), s0 = __shfl(sv, 0, 16);
        float c1 = __shfl(cv, 1, 16), s1 = __shfl(sv, 1, 16);
        float c2 = __shfl(cv, 2, 16), s2 = __shfl(sv, 2, 16);
        float c3 = __shfl(cv, 3, 16), s3 = __shfl(sv, 3, 16);
        float hsd = __shfl(ds, 0, 16);

        if (L < 4) nres1[n * 4 + L] = hv;
        if (L == 0) hdd1[n] = dd;
        prep_node64(L, c0, s0, c1, s1, c2, s2, c3, s3, hsd, gr, gi, sT + nw * 48);
    }
    __syncthreads();
    {
        int n0 = blockIdx.x * 4;
        int cnt = (min(n0 + 4, N) - n0) * 48;
        for (int i = threadIdx.x; i < cnt; i += 256)
            T[(size_t)n0 * 48 + i] = sT[i];
    }
}

// ---------------- offsets (deg+1 incl. self-loop) ----------------
__global__ __launch_bounds__(1024) void k_scan(
    const int* __restrict__ deg, int* __restrict__ off,
    int* __restrict__ cur, int N)
{
    __shared__ int part[1024];
    const int t = threadIdx.x;
    const int chunk = (N + 1023) / 1024;
    const int lo = t * chunk;
    const int hi = min(lo + chunk, N);
    int s = 0;
    for (int i = lo; i < hi; ++i) s += deg[i] + 1;
    part[t] = s;
    __syncthreads();
    for (int d = 1; d < 1024; d <<= 1) {
        int y = (t >= d) ? part[t - d] : 0;
        __syncthreads();
        part[t] += y;
        __syncthreads();
    }
    int run = part[t] - s;
    for (int i = lo; i < hi; ++i) { off[i] = run; cur[i] = run; run += deg[i] + 1; }
}

// ---------------- CSR fill: {src|dst<<16, |ea|, cos, sin} (incl. self-loops) ----------------
__global__ __launch_bounds__(256) void k_fill(
    const int* __restrict__ ei, const float* __restrict__ ea,
    int* __restrict__ cur, float4* __restrict__ rec, int E, int N)
{
    int idx = blockIdx.x * 256 + threadIdx.x;
    if (idx >= E + N) return;
    int src, d; float ev;
    if (idx < E) { src = ei[idx]; d = ei[E + idx]; ev = ea[idx]; }
    else         { src = idx - E; d = src;         ev = 1.0f;    }
    int slot = atomicAdd(&cur[d], 1);
    float scv, ccv; sincosf(0.5f * PI_F * tanhf(ev), &scv, &ccv);
    float4 r;
    r.x = __int_as_float(src | (d << 16));   // N < 65536
    r.y = fabsf(ev);
    r.z = ccv; r.w = scv;
    rec[slot] = r;
}

// segmented wave reduce over equal-dst runs + atomic by segment-last lane
__device__ __forceinline__ void segreduce(
    int dst, int lane, float a0, float a1, float a2, float a3, float a4,
    float* __restrict__ S)
{
    int prevd = __shfl_up(dst, 1);
    bool head = (lane == 0) || (prevd != dst);
    unsigned long long hm = __ballot(head);
    unsigned long long below = (2ull << lane) - 1ull;
    int H = 63 - __clzll((long long)(hm & below));
    int dist = lane - H;
#pragma unroll
    for (int st = 1; st < 64; st <<= 1) {
        float t0 = __shfl_up(a0, st), t1 = __shfl_up(a1, st),
              t2 = __shfl_up(a2, st), t3 = __shfl_up(a3, st),
              t4 = __shfl_up(a4, st);
        if (dist >= st) { a0 += t0; a1 += t1; a2 += t2; a3 += t3; a4 += t4; }
    }
    int nextd = __shfl_down(dst, 1);
    bool lastl = (lane == 63) || (dst != nextd);
    if (lastl && dst >= 0) {
        float* sbase = S + (size_t)dst * 5;
        atomicAdd(sbase + 0, a0); atomicAdd(sbase + 1, a1);
        atomicAdd(sbase + 2, a2); atomicAdd(sbase + 3, a3);
        atomicAdd(sbase + 4, a4);
    }
}

// ---------------- edge kernel: quadratic form z_w = c^T M^w c ----------------
__global__ __launch_bounds__(256) void k_edge(
    const float4* __restrict__ rec, const float* __restrict__ T,
    const float* __restrict__ hdd, float* __restrict__ S, int EN)
{
    const int slot = blockIdx.x * 256 + threadIdx.x;
    const int lane = threadIdx.x & 63;
    int dst = -1;
    float acc0 = 0.f, acc1 = 0.f, acc2 = 0.f, acc3 = 0.f, acc4 = 0.f;

    if (slot < EN) {
        float4 r = rec[slot];
        int ids = __float_as_int(r.x);
        int src = ids & 0xFFFF;
        dst = ids >> 16;
        float aea = r.y, ccv = r.z, scv = r.w;

        const float* Tb = T + (size_t)src * 48;
        float t[44];
#pragma unroll
        for (int q = 0; q < 11; ++q) {
            float4 v4 = *reinterpret_cast<const float4*>(Tb + q * 4);
            t[q * 4 + 0] = v4.x; t[q * 4 + 1] = v4.y;
            t[q * 4 + 2] = v4.z; t[q * 4 + 3] = v4.w;
        }
        float hdN = hdd[dst];

        float mc = t[40] * ccv - t[41] * scv;
        float ms = t[41] * ccv + t[40] * scv;
        float m2 = mc * mc, s2 = ms * ms;
        float cf0 = mc * m2, cf1 = m2 * ms, cf2 = mc * s2, cf3 = ms * s2;
        float qq[10];
        qq[0] = cf0 * cf0; qq[1] = cf0 * cf1; qq[2] = cf0 * cf2; qq[3] = cf0 * cf3;
        qq[4] = cf1 * cf1; qq[5] = cf1 * cf2; qq[6] = cf1 * cf3;
        qq[7] = cf2 * cf2; qq[8] = cf2 * cf3; qq[9] = cf3 * cf3;

        float z0 = 0.f, z1 = 0.f, z2 = 0.f, z3 = 0.f;
#pragma unroll
        for (int pi = 0; pi < 10; ++pi) {
            z0 += t[pi] * qq[pi];
            z1 += t[10 + pi] * qq[pi];
            z2 += t[20 + pi] * qq[pi];
            z3 += t[30 + pi] * qq[pi];
        }

        float s0a = t[42] + hdN;
        s0a = (s0a > 0.f) ? s0a : 0.2f * s0a;
        float aexp = expf(s0a * aea);
        acc0 = aexp * z0; acc1 = aexp * z1; acc2 = aexp * z2; acc3 = aexp * z3;
        acc4 = aexp;
    }
    segreduce(dst, lane, acc0, acc1, acc2, acc3, acc4, S);
}

// ---------------- layer-1 node update (1 wave/node) + FUSED layer-2 prep ----------------
__global__ __launch_bounds__(256) void k_nodeprep(
    const float* __restrict__ S, const float* __restrict__ nres,
    const float* __restrict__ g4, const float* __restrict__ be4,
    const float* __restrict__ pW, const float* __restrict__ pb,
    const float* __restrict__ WaN, const float* __restrict__ Gl,
    float* __restrict__ onres, float* __restrict__ ohdd,
    float* __restrict__ T, int N)
{
    __shared__ float gr[3][16 * 17], gi[3][16 * 17];
    __shared__ float sT[4 * 48];
    for (int idx = threadIdx.x; idx < 3 * 256; idx += 256) {
        int rep = idx >> 8, rc = idx & 255, i = rc >> 4, jj = rc & 15;
        gr[rep][i * 17 + jj] = Gl[rep * 512 + rc * 2 + 0];
        gi[rep][i * 17 + jj] = Gl[rep * 512 + rc * 2 + 1];
    }
    __syncthreads();

    const int L = threadIdx.x & 63;
    const int j = L & 15;
    const int nw = threadIdx.x >> 6;
    const int n = blockIdx.x * 4 + nw;
    const bool valid = (n < N);

    if (valid) {
        // node update replicated across all 64 lanes (free in SIMD issue)
        const float* sb = S + (size_t)n * 5;
        float dn = sb[4] + 1e-8f;
        float v0 = sb[0] / dn + nres[n * 4 + 0];
        float v1 = sb[1] / dn + nres[n * 4 + 1];
        float v2 = sb[2] / dn + nres[n * 4 + 2];
        float v3 = sb[3] / dn + nres[n * 4 + 3];
        float mu = 0.25f * (v0 + v1 + v2 + v3);
        float d0 = v0 - mu, d1 = v1 - mu, d2 = v2 - mu, d3 = v3 - mu;
        float var = 0.25f * (d0 * d0 + d1 * d1 + d2 * d2 + d3 * d3);
        float rs = 1.0f / sqrtf(var + 1e-5f);
        float y0 = fmaxf(d0 * rs * g4[0] + be4[0], 0.f);
        float y1 = fmaxf(d1 * rs * g4[1] + be4[1], 0.f);
        float y2 = fmaxf(d2 * rs * g4[2] + be4[2], 0.f);
        float y3 = fmaxf(d3 * rs * g4[3] + be4[3], 0.f);

        float hv0, hv1, hv2, hv3;
        {
            float s;
            s = pb[0] + y0 * pW[0] + y1 * pW[1] + y2 * pW[2] + y3 * pW[3];
            hv0 = (s > 0.f) ? s : expm1f(s);
            s = pb[1] + y0 * pW[4] + y1 * pW[5] + y2 * pW[6] + y3 * pW[7];
            hv1 = (s > 0.f) ? s : expm1f(s);
            s = pb[2] + y0 * pW[8] + y1 * pW[9] + y2 * pW[10] + y3 * pW[11];
            hv2 = (s > 0.f) ? s : expm1f(s);
            s = pb[3] + y0 * pW[12] + y1 * pW[13] + y2 * pW[14] + y3 * pW[15];
            hv3 = (s > 0.f) ? s : expm1f(s);
        }

        float cv = 1.f, sv = 0.f;
        if (j < 4) {
            float hsel = (j == 0) ? hv0 : (j == 1) ? hv1 : (j == 2) ? hv2 : hv3;
            sincosf(0.5f * PI_F * tanhf(hsel), &sv, &cv);
        }
        float c0 = __shfl(cv, 0, 16), s0 = __shfl(sv, 0, 16);
        float c1 = __shfl(cv, 1, 16), s1 = __shfl(sv, 1, 16);
        float c2 = __shfl(cv, 2, 16), s2 = __shfl(sv, 2, 16);
        float c3 = __shfl(cv, 3, 16), s3 = __shfl(sv, 3, 16);

        float hsd = hv0 * WaN[0] + hv1 * WaN[1] + hv2 * WaN[2] + hv3 * WaN[3];
        if (L < 4) {
            float hsel = (L == 0) ? hv0 : (L == 1) ? hv1 : (L == 2) ? hv2 : hv3;
            onres[n * 4 + L] = hsel;
        }
        if (L == 0)
            ohdd[n] = hv0 * WaN[4] + hv1 * WaN[5] + hv2 * WaN[6] + hv3 * WaN[7];

        prep_node64(L, c0, s0, c1, s1, c2, s2, c3, s3, hsd, gr, gi, sT + nw * 48);
    }
    __syncthreads();
    {
        int n0 = blockIdx.x * 4;
        int cnt = (min(n0 + 4, N) - n0) * 48;
        for (int i = threadIdx.x; i < cnt; i += 256)
            T[(size_t)n0 * 48 + i] = sT[i];
    }
}

// ---------------- final node update: norm + residual + LN + head ----------------
__global__ __launch_bounds__(256) void k_node2(
    const float* __restrict__ S, const float* __restrict__ nres,
    const float* __restrict__ g4, const float* __restrict__ be4,
    const float* __restrict__ rW, const float* __restrict__ rb,
    float* __restrict__ out, int N)
{
    int n = blockIdx.x * 256 + threadIdx.x;
    if (n >= N) return;
    const float* sb = S + (size_t)n * 5;
    float dn = sb[4] + 1e-8f;
    float v0 = sb[0] / dn + nres[n * 4 + 0];
    float v1 = sb[1] / dn + nres[n * 4 + 1];
    float v2 = sb[2] / dn + nres[n * 4 + 2];
    float v3 = sb[3] / dn + nres[n * 4 + 3];
    float mu = 0.25f * (v0 + v1 + v2 + v3);
    float d0 = v0 - mu, d1 = v1 - mu, d2 = v2 - mu, d3 = v3 - mu;
    float var = 0.25f * (d0 * d0 + d1 * d1 + d2 * d2 + d3 * d3);
    float rs = 1.0f / sqrtf(var + 1e-5f);
    out[n] = rb[0]
           + (d0 * rs * g4[0] + be4[0]) * rW[0]
           + (d1 * rs * g4[1] + be4[1]) * rW[1]
           + (d2 * rs * g4[2] + be4[2]) * rW[2]
           + (d3 * rs * g4[3] + be4[3]) * rW[3];
}

extern "C" void kernel_launch(void* const* d_in, const int* in_sizes, int n_in,
                              void* d_out, int out_size, void* d_ws, size_t ws_size,
                              hipStream_t stream)
{
    const float* x    = (const float*)d_in[0];
    const int*   ei   = (const int*)d_in[1];
    const float* ea   = (const float*)d_in[2];
    const float* W_ih = (const float*)d_in[3];
    const float* W_hh = (const float*)d_in[4];
    const float* b_ih = (const float*)d_in[5];
    const float* b_hh = (const float*)d_in[6];
    const float* p1W  = (const float*)d_in[7];
    const float* p1b  = (const float*)d_in[8];
    const float* a1W  = (const float*)d_in[9];
    const float* q1w  = (const float*)d_in[10];
    const float* g1   = (const float*)d_in[11];
    const float* be1  = (const float*)d_in[12];
    const float* p2W  = (const float*)d_in[13];
    const float* p2b  = (const float*)d_in[14];
    const float* a2W  = (const float*)d_in[15];
    const float* q2w  = (const float*)d_in[16];
    const float* g2   = (const float*)d_in[17];
    const float* be2  = (const float*)d_in[18];
    const float* rW   = (const float*)d_in[19];
    const float* rb   = (const float*)d_in[20];
    float* out = (float*)d_out;

    int N  = in_sizes[0] / 13;
    int E  = in_sizes[1] / 2;
    int EN = E + N;

    // workspace layout
    float* ws    = (float*)d_ws;
    float* nres1 = ws;                           // N*4
    float* nres2 = nres1 + (size_t)N * 4;        // N*4
    float* hdd1  = nres2 + (size_t)N * 4;        // N
    float* hdd2  = hdd1 + N;                     // N
    float* S1    = hdd2 + N;                     // N*5 (zeroed in k_gru)
    float* S2    = S1 + (size_t)N * 5;           // N*5 (zeroed in k_gru)
    float* Gtab  = S2 + (size_t)N * 5;           // 3072
    float* T     = Gtab + 3072;                  // N*48 (reused across layers)
    int* deg  = (int*)(T + (size_t)N * 48);      // N (memset)
    int* off  = deg + N;                         // N
    int* cur  = off + N;                         // N
    uintptr_t rp = (uintptr_t)(cur + N);
    rp = (rp + 15u) & ~(uintptr_t)15u;           // 16B align
    float4* rec = (float4*)rp;                   // EN float4

    hipMemsetAsync(deg, 0, (size_t)N * sizeof(int), stream);

    const int B = 256;
    k_gmat<<<1, 128, 0, stream>>>(q1w, q2w, Gtab);
    k_gru<<<(N + 3) / 4, B, 0, stream>>>(x, W_ih, W_hh, b_ih, b_hh, p1W, p1b,
                                         a1W, Gtab, ei, deg, nres1, hdd1, T,
                                         S1, N, E);
    k_scan<<<1, 1024, 0, stream>>>(deg, off, cur, N);
    k_fill<<<(EN + B - 1) / B, B, 0, stream>>>(ei, ea, cur, rec, E, N);

    // layer 1
    k_edge<<<(EN + B - 1) / B, B, 0, stream>>>(rec, T, hdd1, S1, EN);
    k_nodeprep<<<(N + 3) / 4, B, 0, stream>>>(
        S1, nres1, g1, be1, p2W, p2b, a2W, Gtab + 1536, nres2, hdd2, T, N);

    // layer 2
    k_edge<<<(EN + B - 1) / B, B, 0, stream>>>(rec, T, hdd2, S2, EN);
    k_node2<<<(N + B - 1) / B, B, 0, stream>>>(S2, nres2, g2, be2, rW, rb, out, N);
}